// Round 1
// baseline (7378.193 us; speedup 1.0000x reference)
//
#include <hip/hip_runtime.h>

#define B_ 2048
#define S_ 128
#define D_ 1024
#define H_ 2048
#define E_ 8
#define NC 10
#define STEPS_ 5

constexpr int BM = 64, BN = 128, BK = 16;

// ---------------------------------------------------------------------------
// Pool: h[b] = masked mean over S of emb[ids[b,s]]; also init active list.
// ---------------------------------------------------------------------------
__global__ __launch_bounds__(256) void pool_kernel(
    const int* __restrict__ ids, const float* __restrict__ emb,
    float* __restrict__ h, int* __restrict__ al, int* __restrict__ n_act)
{
    const int b = blockIdx.x;
    const int t = threadIdx.x;
    __shared__ int sid[S_];
    __shared__ float scnt;
    if (t < S_) sid[t] = ids[b * S_ + t];
    __syncthreads();
    if (t == 0) {
        int c = 0;
        for (int j = 0; j < S_; j++) c += (sid[j] != 0) ? 1 : 0;
        scnt = (c > 0) ? (float)c : 1.0f;
    }
    const int d0 = t * 4;
    float ax = 0.f, ay = 0.f, az = 0.f, aw = 0.f;
    for (int j = 0; j < S_; j++) {
        const int id = sid[j];
        if (id != 0) {  // wave-uniform branch (sid[j] is broadcast)
            const float4 v = *(const float4*)(emb + (size_t)id * D_ + d0);
            ax += v.x; ay += v.y; az += v.z; aw += v.w;
        }
    }
    __syncthreads();
    const float c = scnt;
    float4 r; r.x = ax / c; r.y = ay / c; r.z = az / c; r.w = aw / c;
    *(float4*)(h + (size_t)b * D_ + d0) = r;
    if (t == 0) {
        al[b] = b;
        if (b == 0) *n_act = B_;
    }
}

// ---------------------------------------------------------------------------
// Generic gathered-row fp32 GEMM:
//   for i in [0, counts[z]):  C[rows[i]] = op( A[rows[i]] @ W_z + bias_z )
// 64x128 tile, 256 threads, 4x8 accumulators per thread, BK=16.
// ---------------------------------------------------------------------------
__global__ __launch_bounds__(256) void gemm_gather(
    const float* __restrict__ A, int a_rs,
    const float* __restrict__ W, long long w_es, int N,
    const float* __restrict__ bias, int bias_es, int has_bias,
    float* __restrict__ C, int c_rs,
    const int* __restrict__ rows, int rows_es,
    const int* __restrict__ counts,
    int K, int do_relu)
{
    const int e = blockIdx.z;
    const int cnt = counts[e];
    const int m0 = blockIdx.x * BM;
    if (m0 >= cnt) return;
    const int n0 = blockIdx.y * BN;

    const float* We = W + (size_t)e * (size_t)w_es + n0;
    const int* rowse = rows + (size_t)e * rows_es;

    __shared__ float As[BK][BM + 4];   // stride 68 floats -> 16B-aligned rows
    __shared__ float Bs[BK][BN];

    const int tid = threadIdx.x;
    // A load: 64 rows x 16 k / 256 thr = one float4 each
    const int l_ar = tid >> 2;
    const int l_ak = (tid & 3) << 2;
    const int arow_i = m0 + l_ar;
    const int arow = rowse[arow_i < cnt ? arow_i : (cnt - 1)];
    const float* Ap = A + (size_t)arow * a_rs + l_ak;
    // B load: 16 k x 128 n / 256 thr = two float4 each (k and k+8)
    const int l_bk = tid >> 5;
    const int l_bn = (tid & 31) << 2;
    const float* Bp = We + (size_t)l_bk * N + l_bn;

    const int tx = tid & 15;   // col group (x8)
    const int ty = tid >> 4;   // row group (x4)

    float acc[4][8];
#pragma unroll
    for (int i = 0; i < 4; i++)
#pragma unroll
        for (int j = 0; j < 8; j++) acc[i][j] = 0.f;

    float4 av  = *(const float4*)(Ap);
    float4 bv0 = *(const float4*)(Bp);
    float4 bv1 = *(const float4*)(Bp + (size_t)8 * N);

    for (int k0 = 0; k0 < K; k0 += BK) {
        __syncthreads();
        As[l_ak + 0][l_ar] = av.x;
        As[l_ak + 1][l_ar] = av.y;
        As[l_ak + 2][l_ar] = av.z;
        As[l_ak + 3][l_ar] = av.w;
        *(float4*)&Bs[l_bk][l_bn] = bv0;
        *(float4*)&Bs[l_bk + 8][l_bn] = bv1;
        __syncthreads();
        if (k0 + BK < K) {
            av  = *(const float4*)(Ap + (k0 + BK));
            bv0 = *(const float4*)(Bp + (size_t)(k0 + BK) * N);
            bv1 = *(const float4*)(Bp + (size_t)(k0 + BK + 8) * N);
        }
#pragma unroll
        for (int k = 0; k < BK; k++) {
            const float4 a  = *(const float4*)&As[k][ty * 4];
            const float4 b0 = *(const float4*)&Bs[k][tx * 8];
            const float4 b1 = *(const float4*)&Bs[k][tx * 8 + 4];
            const float ar[4] = {a.x, a.y, a.z, a.w};
            const float br[8] = {b0.x, b0.y, b0.z, b0.w, b1.x, b1.y, b1.z, b1.w};
#pragma unroll
            for (int i = 0; i < 4; i++)
#pragma unroll
                for (int j = 0; j < 8; j++)
                    acc[i][j] = fmaf(ar[i], br[j], acc[i][j]);
        }
    }

    const float* be = has_bias ? (bias + (size_t)e * bias_es + n0) : nullptr;
    float bb[8];
    if (has_bias) {
#pragma unroll
        for (int j = 0; j < 8; j++) bb[j] = be[tx * 8 + j];
    }
#pragma unroll
    for (int i = 0; i < 4; i++) {
        const int mi = m0 + ty * 4 + i;
        if (mi < cnt) {
            const int r = rowse[mi];
            float* Cr = C + (size_t)r * c_rs + n0 + tx * 8;
            float v[8];
#pragma unroll
            for (int j = 0; j < 8; j++) {
                float x = acc[i][j];
                if (has_bias) x += bb[j];
                if (do_relu) x = fmaxf(x, 0.f);
                v[j] = x;
            }
            float4 v0 = {v[0], v[1], v[2], v[3]};
            float4 v1 = {v[4], v[5], v[6], v[7]};
            *(float4*)(Cr) = v0;
            *(float4*)(Cr + 4) = v1;
        }
    }
}

// ---------------------------------------------------------------------------
// Router stage 2: logits = rhid @ rW2 + rb2 (per active sample), argmax,
// terminate (copy h->final) or bucket into per-expert lists + next active list.
// One wave per sample.
// ---------------------------------------------------------------------------
__global__ __launch_bounds__(256) void router2_kernel(
    const float* __restrict__ rhid, const float* __restrict__ rW2,
    const float* __restrict__ rb2, const float* __restrict__ h,
    float* __restrict__ final_, const int* __restrict__ al,
    const int* __restrict__ n_act, int* __restrict__ counts,
    int* __restrict__ bucket, int* __restrict__ al_next,
    int* __restrict__ n_next, int* __restrict__ act_sel)
{
    const int n = *n_act;
    const int wid = threadIdx.x >> 6;
    const int lane = threadIdx.x & 63;
    const int i = blockIdx.x * 4 + wid;
    if (i >= n) return;
    const int s = al[i];
    const float* x = rhid + (size_t)s * D_;
    float acc[E_ + 1];
#pragma unroll
    for (int c = 0; c <= E_; c++) acc[c] = 0.f;
    for (int j = 0; j < D_ / 64; j++) {
        const int d = j * 64 + lane;
        const float xv = x[d];
        const float* wr = rW2 + (size_t)d * (E_ + 1);
#pragma unroll
        for (int c = 0; c <= E_; c++) acc[c] = fmaf(xv, wr[c], acc[c]);
    }
#pragma unroll
    for (int c = 0; c <= E_; c++) {
        float v = acc[c];
        for (int off = 32; off > 0; off >>= 1) v += __shfl_down(v, off, 64);
        acc[c] = v;
    }
    int best = 0;
    if (lane == 0) {
        float bv = acc[0] + rb2[0];
#pragma unroll
        for (int c = 1; c <= E_; c++) {
            const float v = acc[c] + rb2[c];
            if (v > bv) { bv = v; best = c; }   // strict '>' = first-max (np argmax)
        }
    }
    best = __shfl(best, 0, 64);
    if (best == E_) {
        const float* hs = h + (size_t)s * D_;
        float* fs = final_ + (size_t)s * D_;
        for (int d = lane * 4; d < D_; d += 64 * 4)
            *(float4*)(fs + d) = *(const float4*)(hs + d);
    } else if (lane == 0) {
        const int p = atomicAdd(&counts[best], 1);
        bucket[best * B_ + p] = s;
        const int q = atomicAdd(n_next, 1);
        al_next[q] = s;
        act_sel[s] = best;
    }
}

// ---------------------------------------------------------------------------
// LN + residual: h[s] += LN(Y[s] + b2_e) * g_e + beta_e  for routed samples.
// One block per sample (ghost blocks exit).
// ---------------------------------------------------------------------------
__global__ __launch_bounds__(256) void ln_update_kernel(
    float* __restrict__ h, const float* __restrict__ Y,
    const float* __restrict__ eb2, const float* __restrict__ eg,
    const float* __restrict__ ebeta, const int* __restrict__ al,
    const int* __restrict__ n_ptr, const int* __restrict__ act_sel)
{
    const int n = *n_ptr;
    const int i = blockIdx.x;
    if (i >= n) return;
    const int s = al[i];
    const int e = act_sel[s];
    const int t = threadIdx.x;
    const int lane = t & 63, wid = t >> 6;
    const int d0 = t * 4;

    const float4 yv = *(const float4*)(Y + (size_t)s * D_ + d0);
    const float4 bv = *(const float4*)(eb2 + (size_t)e * D_ + d0);
    float y0 = yv.x + bv.x, y1 = yv.y + bv.y, y2 = yv.z + bv.z, y3 = yv.w + bv.w;

    __shared__ float wsum[4];
    __shared__ float stats[2];

    float ssum = y0 + y1 + y2 + y3;
    for (int off = 32; off > 0; off >>= 1) ssum += __shfl_down(ssum, off, 64);
    if (lane == 0) wsum[wid] = ssum;
    __syncthreads();
    if (t == 0) stats[0] = (wsum[0] + wsum[1] + wsum[2] + wsum[3]) * (1.f / D_);
    __syncthreads();
    const float m = stats[0];
    const float e0 = y0 - m, e1 = y1 - m, e2 = y2 - m, e3 = y3 - m;
    float sq = e0 * e0 + e1 * e1 + e2 * e2 + e3 * e3;
    for (int off = 32; off > 0; off >>= 1) sq += __shfl_down(sq, off, 64);
    if (lane == 0) wsum[wid] = sq;
    __syncthreads();
    if (t == 0) {
        const float var = (wsum[0] + wsum[1] + wsum[2] + wsum[3]) * (1.f / D_);
        stats[1] = 1.0f / sqrtf(var + 1e-5f);
    }
    __syncthreads();
    const float rs = stats[1];

    const float4 gv = *(const float4*)(eg + (size_t)e * D_ + d0);
    const float4 btv = *(const float4*)(ebeta + (size_t)e * D_ + d0);
    float* hp = h + (size_t)s * D_ + d0;
    float4 hv = *(const float4*)hp;
    hv.x += e0 * rs * gv.x + btv.x;
    hv.y += e1 * rs * gv.y + btv.y;
    hv.z += e2 * rs * gv.z + btv.z;
    hv.w += e3 * rs * gv.w + btv.w;
    *(float4*)hp = hv;
}

__global__ void reset_kernel(int* __restrict__ counts, int* __restrict__ n_next)
{
    const int t = threadIdx.x;
    if (t < E_) counts[t] = 0;
    if (t == E_) *n_next = 0;
}

__global__ __launch_bounds__(256) void finalize_kernel(
    const int* __restrict__ al, const int* __restrict__ n_ptr,
    const float* __restrict__ h, float* __restrict__ final_)
{
    const int n = *n_ptr;
    const int i = blockIdx.x;
    if (i >= n) return;
    const int s = al[i];
    const int d0 = threadIdx.x * 4;
    *(float4*)(final_ + (size_t)s * D_ + d0) =
        *(const float4*)(h + (size_t)s * D_ + d0);
}

// out[s, 0..9] = final[s] @ oW + ob
__global__ __launch_bounds__(256) void out_head_kernel(
    const float* __restrict__ final_, const float* __restrict__ oW,
    const float* __restrict__ ob, float* __restrict__ out)
{
    const int s = blockIdx.x;
    const int t = threadIdx.x;
    const int lane = t & 63, wid = t >> 6;
    float p[NC];
#pragma unroll
    for (int c = 0; c < NC; c++) p[c] = 0.f;
    for (int d = t; d < D_; d += 256) {
        const float x = final_[(size_t)s * D_ + d];
        const float* wr = oW + (size_t)d * NC;
#pragma unroll
        for (int c = 0; c < NC; c++) p[c] = fmaf(x, wr[c], p[c]);
    }
#pragma unroll
    for (int c = 0; c < NC; c++) {
        float v = p[c];
        for (int off = 32; off > 0; off >>= 1) v += __shfl_down(v, off, 64);
        p[c] = v;
    }
    __shared__ float red[4][NC];
    if (lane == 0) {
#pragma unroll
        for (int c = 0; c < NC; c++) red[wid][c] = p[c];
    }
    __syncthreads();
    if (t < NC)
        out[(size_t)s * NC + t] =
            red[0][t] + red[1][t] + red[2][t] + red[3][t] + ob[t];
}

// ---------------------------------------------------------------------------
extern "C" void kernel_launch(void* const* d_in, const int* in_sizes, int n_in,
                              void* d_out, int out_size, void* d_ws, size_t ws_size,
                              hipStream_t stream)
{
    const int*   ids   = (const int*)d_in[0];
    const float* emb   = (const float*)d_in[1];
    const float* rW1   = (const float*)d_in[2];
    const float* rb1   = (const float*)d_in[3];
    const float* rW2   = (const float*)d_in[4];
    const float* rb2   = (const float*)d_in[5];
    const float* eW1   = (const float*)d_in[6];
    const float* eb1   = (const float*)d_in[7];
    const float* eW2   = (const float*)d_in[8];
    const float* eb2   = (const float*)d_in[9];
    const float* eg    = (const float*)d_in[10];
    const float* ebeta = (const float*)d_in[11];
    const float* oW    = (const float*)d_in[12];
    const float* ob    = (const float*)d_in[13];
    float* out = (float*)d_out;

    // workspace layout (fp32 buffers first, then ints)
    float* h     = (float*)d_ws;                 // B*D
    float* fin   = h + (size_t)B_ * D_;          // B*D
    float* rhidY = fin + (size_t)B_ * D_;        // B*D (router hidden, reused as Y)
    float* Z     = rhidY + (size_t)B_ * D_;      // B*H
    int* alA     = (int*)(Z + (size_t)B_ * H_);  // B
    int* alB     = alA + B_;                     // B
    int* bucket  = alB + B_;                     // E*B
    int* counts  = bucket + E_ * B_;             // E
    int* nA      = counts + E_;                  // 1
    int* nB      = nA + 1;                       // 1
    int* act_sel = nB + 1;                       // B

    pool_kernel<<<B_, 256, 0, stream>>>(ids, emb, h, alA, nA);

    int* al_in = alA; int* n_in_p = nA;
    int* al_out = alB; int* n_out_p = nB;

    for (int step = 0; step < STEPS_; step++) {
        reset_kernel<<<1, 64, 0, stream>>>(counts, n_out_p);

        // router hidden: rhid = relu(h @ rW1 + rb1), gathered over active list
        gemm_gather<<<dim3(B_ / BM, D_ / BN, 1), 256, 0, stream>>>(
            h, D_, rW1, 0, D_, rb1, 0, 1, rhidY, D_, al_in, 0, n_in_p, D_, 1);

        router2_kernel<<<B_ / 4, 256, 0, stream>>>(
            rhidY, rW2, rb2, h, fin, al_in, n_in_p,
            counts, bucket, al_out, n_out_p, act_sel);

        // expert layer 1: Z = relu(h @ eW1_e + eb1_e) for bucketed samples
        gemm_gather<<<dim3(B_ / BM, H_ / BN, E_), 256, 0, stream>>>(
            h, D_, eW1, (long long)D_ * H_, H_, eb1, H_, 1,
            Z, H_, bucket, B_, counts, D_, 1);

        // expert layer 2: Y = Z @ eW2_e (bias folded into LN kernel)
        gemm_gather<<<dim3(B_ / BM, D_ / BN, E_), 256, 0, stream>>>(
            Z, H_, eW2, (long long)H_ * D_, D_, nullptr, 0, 0,
            rhidY, D_, bucket, B_, counts, H_, 0);

        ln_update_kernel<<<B_, 256, 0, stream>>>(
            h, rhidY, eb2, eg, ebeta, al_out, n_out_p, act_sel);

        // swap active lists
        int* ta = al_in; al_in = al_out; al_out = ta;
        int* tn = n_in_p; n_in_p = n_out_p; n_out_p = tn;
    }

    finalize_kernel<<<B_, 256, 0, stream>>>(al_in, n_in_p, h, fin);
    out_head_kernel<<<B_, 256, 0, stream>>>(fin, oW, ob, out);
}